// Round 1
// baseline (10809.621 us; speedup 1.0000x reference)
//
#include <hip/hip_runtime.h>
#include <hip/hip_bf16.h>

// StandardAttention: B=4, H=16, S=2048, D=64, fp32 in/out.
// out[b, q, h*64 + d] = softmax(Q K^T / 8)[b,h,q,:] . V[b,h,:,d]
//
// Flash-style online softmax, pure fp32 vector ALU (no fp32 MFMA on CDNA4).
// One block (256 thr) handles one (b,h) x 64-query tile; loops over 32
// key tiles of 64. LDS rows padded to 68 floats so strided row reads are
// <=2-way bank aliased (free).

#define B_ 4
#define H_ 16
#define S_ 2048
#define D_ 64
#define TQ 64
#define TK 64
#define LSTR 68   // LDS row stride in floats (68*4=272B, 16B-aligned, odd bank phase)

__global__ __launch_bounds__(256, 2)
void attn_fwd_f32(const float* __restrict__ Q, const float* __restrict__ K,
                  const float* __restrict__ V, float* __restrict__ O) {
  __shared__ float Qs[TQ][LSTR];
  __shared__ float Ks[TK][LSTR];
  __shared__ float Vs[TK][LSTR];
  __shared__ float Ss[TQ][LSTR];
  __shared__ float m_lds[TQ];
  __shared__ float l_lds[TQ];
  __shared__ float alpha_lds[TQ];

  const int t  = threadIdx.x;         // 0..255
  const int bh = blockIdx.y;          // b*H + h
  const int q0 = blockIdx.x * TQ;
  const int tq = t >> 4;              // 0..15  (16-lane cluster id)
  const int tk = t & 15;              // 0..15  (lane within cluster)

  // ---- load Q tile, fold in 1/sqrt(64) = 0.125 (exact) ----
  const float* Qg = Q + ((size_t)bh * S_ + q0) * D_;
  #pragma unroll
  for (int r = 0; r < 4; ++r) {
    int f = r * 256 + t;                    // float4 index within 64x64 tile
    int row = f >> 4, col = (f & 15) << 2;
    float4 v = *(const float4*)(Qg + row * D_ + col);
    v.x *= 0.125f; v.y *= 0.125f; v.z *= 0.125f; v.w *= 0.125f;
    *(float4*)&Qs[row][col] = v;
  }
  if (t < TQ) { m_lds[t] = -1e30f; l_lds[t] = 0.0f; }

  float4 acc[4];
  #pragma unroll
  for (int i = 0; i < 4; ++i) acc[i] = make_float4(0.f, 0.f, 0.f, 0.f);

  for (int kt = 0; kt < S_ / TK; ++kt) {
    __syncthreads();  // prev PV done before overwriting Ks/Vs (covers Q/init on iter 0)

    // ---- stage K,V tiles ----
    const float* Kg = K + ((size_t)bh * S_ + kt * TK) * D_;
    const float* Vg = V + ((size_t)bh * S_ + kt * TK) * D_;
    #pragma unroll
    for (int r = 0; r < 4; ++r) {
      int f = r * 256 + t;
      int row = f >> 4, col = (f & 15) << 2;
      *(float4*)&Ks[row][col] = *(const float4*)(Kg + row * D_ + col);
      *(float4*)&Vs[row][col] = *(const float4*)(Vg + row * D_ + col);
    }
    __syncthreads();

    // ---- scores: thread computes rows q = tq+16i, cols k = tk+16j ----
    float s[4][4];
    #pragma unroll
    for (int i = 0; i < 4; ++i)
      #pragma unroll
      for (int j = 0; j < 4; ++j) s[i][j] = 0.f;

    #pragma unroll
    for (int d4 = 0; d4 < D_; d4 += 4) {
      float4 qv[4], kv[4];
      #pragma unroll
      for (int i = 0; i < 4; ++i) qv[i] = *(const float4*)&Qs[tq + 16 * i][d4];
      #pragma unroll
      for (int j = 0; j < 4; ++j) kv[j] = *(const float4*)&Ks[tk + 16 * j][d4];
      #pragma unroll
      for (int i = 0; i < 4; ++i)
        #pragma unroll
        for (int j = 0; j < 4; ++j)
          s[i][j] += qv[i].x * kv[j].x + qv[i].y * kv[j].y +
                     qv[i].z * kv[j].z + qv[i].w * kv[j].w;
    }

    // ---- online softmax per row (row lives in one 16-lane cluster) ----
    #pragma unroll
    for (int i = 0; i < 4; ++i) {
      const int q = tq + 16 * i;
      float rm = fmaxf(fmaxf(s[i][0], s[i][1]), fmaxf(s[i][2], s[i][3]));
      #pragma unroll
      for (int mask = 1; mask < 16; mask <<= 1)
        rm = fmaxf(rm, __shfl_xor(rm, mask));
      const float m_old = m_lds[q];             // wave-uniform per cluster; read-before-write in program order
      const float m_new = fmaxf(m_old, rm);
      float p0 = __expf(s[i][0] - m_new);
      float p1 = __expf(s[i][1] - m_new);
      float p2 = __expf(s[i][2] - m_new);
      float p3 = __expf(s[i][3] - m_new);
      Ss[q][tk]      = p0;
      Ss[q][tk + 16] = p1;
      Ss[q][tk + 32] = p2;
      Ss[q][tk + 48] = p3;
      float rs = p0 + p1 + p2 + p3;
      #pragma unroll
      for (int mask = 1; mask < 16; mask <<= 1)
        rs += __shfl_xor(rs, mask);
      if (tk == 0) {
        const float alpha = __expf(m_old - m_new);
        m_lds[q] = m_new;
        l_lds[q] = l_lds[q] * alpha + rs;
        alpha_lds[q] = alpha;
      }
    }
    __syncthreads();  // Ss + alpha visible to all for PV

    // ---- PV: thread owns rows q = tq+16i, dims d = 4*tk .. 4*tk+3 ----
    {
      const int d4 = tk << 2;
      #pragma unroll
      for (int i = 0; i < 4; ++i) {
        const float a = alpha_lds[tq + 16 * i];
        acc[i].x *= a; acc[i].y *= a; acc[i].z *= a; acc[i].w *= a;
      }
      #pragma unroll 4
      for (int kq = 0; kq < 16; ++kq) {
        const int k = kq << 2;
        float4 vv0 = *(const float4*)&Vs[k + 0][d4];
        float4 vv1 = *(const float4*)&Vs[k + 1][d4];
        float4 vv2 = *(const float4*)&Vs[k + 2][d4];
        float4 vv3 = *(const float4*)&Vs[k + 3][d4];
        #pragma unroll
        for (int i = 0; i < 4; ++i) {
          float4 pr = *(const float4*)&Ss[tq + 16 * i][k];
          acc[i].x += pr.x * vv0.x + pr.y * vv1.x + pr.z * vv2.x + pr.w * vv3.x;
          acc[i].y += pr.x * vv0.y + pr.y * vv1.y + pr.z * vv2.y + pr.w * vv3.y;
          acc[i].z += pr.x * vv0.z + pr.y * vv1.z + pr.z * vv2.z + pr.w * vv3.z;
          acc[i].w += pr.x * vv0.w + pr.y * vv1.w + pr.z * vv2.w + pr.w * vv3.w;
        }
      }
    }
  }

  // ---- epilogue: O[b, q, h*64+d] = acc / l ----
  const int b = bh / H_;
  const int h = bh % H_;
  const int d4 = tk << 2;
  #pragma unroll
  for (int i = 0; i < 4; ++i) {
    const int qloc = tq + 16 * i;
    const float inv = 1.0f / l_lds[qloc];
    float4 o = acc[i];
    o.x *= inv; o.y *= inv; o.z *= inv; o.w *= inv;
    float* dst = O + (((size_t)b * S_ + (q0 + qloc)) * H_ + h) * D_ + d4;
    *(float4*)dst = o;
  }
}

extern "C" void kernel_launch(void* const* d_in, const int* in_sizes, int n_in,
                              void* d_out, int out_size, void* d_ws, size_t ws_size,
                              hipStream_t stream) {
  const float* Q = (const float*)d_in[0];
  const float* K = (const float*)d_in[1];
  const float* V = (const float*)d_in[2];
  float* Out = (float*)d_out;
  dim3 grid(S_ / TQ, B_ * H_);
  dim3 block(256);
  hipLaunchKernelGGL(attn_fwd_f32, grid, block, 0, stream, Q, K, V, Out);
}

// Round 2
// 441.129 us; speedup vs baseline: 24.5044x; 24.5044x over previous
//
#include <hip/hip_runtime.h>

// StandardAttention B=4,H=16,S=2048,D=64 fp32 -> out [B,S,H*D] fp32.
// MFMA (16x16x32 bf16) flash attention, precision-split QK^T.
// wave = 16 queries; block = 4 waves = 64 queries; k-tiles of 64.

#define B_ 4
#define H_ 16
#define S_ 2048
#define D_ 64
#define KQ_STR 72   // bf16 row stride for Q/K tiles (144B: b64-write & b128-read aligned, <=2-way banks)
#define VP_STR 76   // bf16 row stride for Vt/P tiles (152B: b32-write & b64-read aligned, <=2-way banks)

typedef float  f4 __attribute__((ext_vector_type(4)));
typedef short  s4 __attribute__((ext_vector_type(4)));
typedef short  s8 __attribute__((ext_vector_type(8)));

// bf16 round-to-nearest-even
__device__ __forceinline__ unsigned short f2bf(float x) {
  unsigned int u = __float_as_uint(x);
  u += 0x7fffu + ((u >> 16) & 1u);
  return (unsigned short)(u >> 16);
}
// truncation split: hi = trunc bf16, lo = trunc bf16 of remainder (combined rel err ~2^-16)
__device__ __forceinline__ void splitbf(float x, unsigned short& hi, unsigned short& lo) {
  unsigned int u = __float_as_uint(x);
  hi = (unsigned short)(u >> 16);
  float hf = __uint_as_float(u & 0xffff0000u);
  lo = (unsigned short)(__float_as_uint(x - hf) >> 16);
}

__global__ __launch_bounds__(256, 2)
void attn_mfma(const float* __restrict__ Q, const float* __restrict__ K,
               const float* __restrict__ V, float* __restrict__ O) {
  __shared__ __align__(16) unsigned short Qh[64][KQ_STR];
  __shared__ __align__(16) unsigned short Ql[64][KQ_STR];
  __shared__ __align__(16) unsigned short Kh[64][KQ_STR];
  __shared__ __align__(16) unsigned short Kl[64][KQ_STR];
  __shared__ __align__(16) unsigned short Vt[64][VP_STR];      // [dim][key], key-pairs packed as dwords
  __shared__ __align__(16) unsigned short Pb[4][16][VP_STR];   // per-wave P (A-layout source)

  const int t    = threadIdx.x;
  const int w    = t >> 6;          // wave 0..3
  const int lane = t & 63;
  const int g    = lane >> 4;       // quad 0..3
  const int ln   = lane & 15;
  const int bh   = blockIdx.x;      // 0..63  (same-bh q-blocks share XCD via %8 round-robin)
  const int q0   = blockIdx.y * 64;
  const size_t base = (size_t)bh * S_ * D_;

  // ---- stage Q (x0.125 exact, split hi/lo) ----
  {
    const float* Qg = Q + base + (size_t)q0 * D_;
    #pragma unroll
    for (int r = 0; r < 4; ++r) {
      int f = r * 256 + t, row = f >> 4, c4 = (f & 15) << 2;
      float4 v = *(const float4*)(Qg + row * 64 + c4);
      float x0 = v.x * 0.125f, x1 = v.y * 0.125f, x2 = v.z * 0.125f, x3 = v.w * 0.125f;
      s4 hv, lv; unsigned short hb, lb;
      splitbf(x0, hb, lb); hv[0] = (short)hb; lv[0] = (short)lb;
      splitbf(x1, hb, lb); hv[1] = (short)hb; lv[1] = (short)lb;
      splitbf(x2, hb, lb); hv[2] = (short)hb; lv[2] = (short)lb;
      splitbf(x3, hb, lb); hv[3] = (short)hb; lv[3] = (short)lb;
      *(s4*)&Qh[row][c4] = hv;
      *(s4*)&Ql[row][c4] = lv;
    }
  }
  __syncthreads();

  // Q fragments to registers (A-layout: m=ln, k=ks*32+8g+j), never restaged
  s8 qfh[2], qfl[2];
  #pragma unroll
  for (int ks = 0; ks < 2; ++ks) {
    qfh[ks] = *(const s8*)&Qh[16 * w + ln][ks * 32 + 8 * g];
    qfl[ks] = *(const s8*)&Ql[16 * w + ln][ks * 32 + 8 * g];
  }

  f4 oacc[4];
  float m[4], l[4];
  #pragma unroll
  for (int i = 0; i < 4; ++i) { oacc[i] = (f4)0.0f; m[i] = -1e30f; l[i] = 0.0f; }

  const float* Kg = K + base;
  const float* Vg = V + base;
  float4 kreg[4], vreg[4];

  // prefetch tile 0 into registers
  {
    #pragma unroll
    for (int r = 0; r < 4; ++r) {
      int f = r * 256 + t, row = f >> 4, c4 = (f & 15) << 2;
      kreg[r] = *(const float4*)(Kg + row * 64 + c4);
    }
    #pragma unroll
    for (int j = 0; j < 2; ++j) {
      int it = j * 256 + t, kp = it >> 4, c4 = (it & 15) << 2;
      vreg[2 * j]     = *(const float4*)(Vg + (2 * kp) * 64 + c4);
      vreg[2 * j + 1] = *(const float4*)(Vg + (2 * kp + 1) * 64 + c4);
    }
  }

  for (int kt = 0; kt < S_ / 64; ++kt) {
    __syncthreads();  // (a) all waves done reading prev K/V tiles

    // ---- write K tile (split) from prefetched regs ----
    #pragma unroll
    for (int r = 0; r < 4; ++r) {
      int f = r * 256 + t, row = f >> 4, c4 = (f & 15) << 2;
      float4 v = kreg[r];
      s4 hv, lv; unsigned short hb, lb;
      splitbf(v.x, hb, lb); hv[0] = (short)hb; lv[0] = (short)lb;
      splitbf(v.y, hb, lb); hv[1] = (short)hb; lv[1] = (short)lb;
      splitbf(v.z, hb, lb); hv[2] = (short)hb; lv[2] = (short)lb;
      splitbf(v.w, hb, lb); hv[3] = (short)hb; lv[3] = (short)lb;
      *(s4*)&Kh[row][c4] = hv;
      *(s4*)&Kl[row][c4] = lv;
    }
    // ---- write V tile transposed, key-pairs packed into dwords ----
    #pragma unroll
    for (int j = 0; j < 2; ++j) {
      int it = j * 256 + t, kp = it >> 4, c4 = (it & 15) << 2;
      float4 a = vreg[2 * j], b = vreg[2 * j + 1];
      float xa[4] = {a.x, a.y, a.z, a.w};
      float xb[4] = {b.x, b.y, b.z, b.w};
      #pragma unroll
      for (int i = 0; i < 4; ++i) {
        unsigned int pk = (unsigned int)f2bf(xa[i]) | ((unsigned int)f2bf(xb[i]) << 16);
        *(unsigned int*)&Vt[c4 + i][2 * kp] = pk;
      }
    }
    // prefetch next tile while this tile is consumed
    if (kt + 1 < S_ / 64) {
      const float* Kt = Kg + (size_t)(kt + 1) * 64 * 64;
      const float* Vn = Vg + (size_t)(kt + 1) * 64 * 64;
      #pragma unroll
      for (int r = 0; r < 4; ++r) {
        int f = r * 256 + t, row = f >> 4, c4 = (f & 15) << 2;
        kreg[r] = *(const float4*)(Kt + row * 64 + c4);
      }
      #pragma unroll
      for (int j = 0; j < 2; ++j) {
        int it = j * 256 + t, kp = it >> 4, c4 = (it & 15) << 2;
        vreg[2 * j]     = *(const float4*)(Vn + (2 * kp) * 64 + c4);
        vreg[2 * j + 1] = *(const float4*)(Vn + (2 * kp + 1) * 64 + c4);
      }
    }
    __syncthreads();  // (b) staged K/V visible

    // ---- QK^T: 4 n-tiles x 2 k-steps x 3 split MFMAs ----
    f4 sacc[4];
    #pragma unroll
    for (int nt = 0; nt < 4; ++nt) sacc[nt] = (f4)0.0f;
    #pragma unroll
    for (int nt = 0; nt < 4; ++nt) {
      #pragma unroll
      for (int ks = 0; ks < 2; ++ks) {
        s8 kh = *(const s8*)&Kh[16 * nt + ln][ks * 32 + 8 * g];
        s8 kl = *(const s8*)&Kl[16 * nt + ln][ks * 32 + 8 * g];
        sacc[nt] = __builtin_amdgcn_mfma_f32_16x16x32_bf16(qfh[ks], kh, sacc[nt], 0, 0, 0);
        sacc[nt] = __builtin_amdgcn_mfma_f32_16x16x32_bf16(qfl[ks], kh, sacc[nt], 0, 0, 0);
        sacc[nt] = __builtin_amdgcn_mfma_f32_16x16x32_bf16(qfh[ks], kl, sacc[nt], 0, 0, 0);
      }
    }

    // ---- online softmax; lane owns rows 4g+r (C-layout) ----
    #pragma unroll
    for (int r = 0; r < 4; ++r) {
      float rm = fmaxf(fmaxf(sacc[0][r], sacc[1][r]), fmaxf(sacc[2][r], sacc[3][r]));
      rm = fmaxf(rm, __shfl_xor(rm, 1));
      rm = fmaxf(rm, __shfl_xor(rm, 2));
      rm = fmaxf(rm, __shfl_xor(rm, 4));
      rm = fmaxf(rm, __shfl_xor(rm, 8));
      float mn = fmaxf(m[r], rm);
      float alpha = __expf(m[r] - mn);
      m[r] = mn;
      float p0 = __expf(sacc[0][r] - mn);
      float p1 = __expf(sacc[1][r] - mn);
      float p2 = __expf(sacc[2][r] - mn);
      float p3 = __expf(sacc[3][r] - mn);
      float rs = p0 + p1 + p2 + p3;
      rs += __shfl_xor(rs, 1);
      rs += __shfl_xor(rs, 2);
      rs += __shfl_xor(rs, 4);
      rs += __shfl_xor(rs, 8);
      l[r] = l[r] * alpha + rs;
      oacc[0][r] *= alpha; oacc[1][r] *= alpha;
      oacc[2][r] *= alpha; oacc[3][r] *= alpha;
      const int row = 4 * g + r;
      Pb[w][row][ln]      = f2bf(p0);
      Pb[w][row][ln + 16] = f2bf(p1);
      Pb[w][row][ln + 32] = f2bf(p2);
      Pb[w][row][ln + 48] = f2bf(p3);
    }

    // ---- PV: per-wave P round-trip (same-wave LDS, no barrier needed) ----
    #pragma unroll
    for (int ks = 0; ks < 2; ++ks) {
      s4 pa0 = *(const s4*)&Pb[w][ln][ks * 32 + 8 * g];
      s4 pa1 = *(const s4*)&Pb[w][ln][ks * 32 + 8 * g + 4];
      s8 pa = __builtin_shufflevector(pa0, pa1, 0, 1, 2, 3, 4, 5, 6, 7);
      #pragma unroll
      for (int dt = 0; dt < 4; ++dt) {
        s4 vb0 = *(const s4*)&Vt[16 * dt + ln][ks * 32 + 8 * g];
        s4 vb1 = *(const s4*)&Vt[16 * dt + ln][ks * 32 + 8 * g + 4];
        s8 vb = __builtin_shufflevector(vb0, vb1, 0, 1, 2, 3, 4, 5, 6, 7);
        oacc[dt] = __builtin_amdgcn_mfma_f32_16x16x32_bf16(pa, vb, oacc[dt], 0, 0, 0);
      }
    }
  }

  // ---- epilogue: O[b, q, h*64+d] = oacc / l ----
  const int b = bh >> 4, h = bh & 15;
  #pragma unroll
  for (int r = 0; r < 4; ++r) {
    const int q = q0 + 16 * w + 4 * g + r;
    const float inv = 1.0f / l[r];
    float* dst = O + ((size_t)b * S_ + q) * (H_ * D_) + h * 64;
    #pragma unroll
    for (int dt = 0; dt < 4; ++dt)
      dst[16 * dt + ln] = oacc[dt][r] * inv;
  }
}

extern "C" void kernel_launch(void* const* d_in, const int* in_sizes, int n_in,
                              void* d_out, int out_size, void* d_ws, size_t ws_size,
                              hipStream_t stream) {
  const float* Q = (const float*)d_in[0];
  const float* K = (const float*)d_in[1];
  const float* V = (const float*)d_in[2];
  float* Out = (float*)d_out;
  dim3 grid(B_ * H_, S_ / 64);  // x = bh (XCD-local K/V reuse), y = q-tile
  dim3 block(256);
  hipLaunchKernelGGL(attn_mfma, grid, block, 0, stream, Q, K, V, Out);
}